// Round 1
// baseline (116.427 us; speedup 1.0000x reference)
//
#include <hip/hip_runtime.h>
#include <math.h>

// LIF router: I = seq @ W^T + b  (GEMM), then sequential leaky-integrate scan
// U = min(beta*U + I_t, 1) over T, then softmax over E.
//
// Exploit: min(.,1) is 1-Lipschitz and beta=0.9, so influence of timestep t on
// U_final is <= 0.9^(T-1-t). Truncating to the last KTAIL=512 steps gives error
// <= |U| * 0.9^512 ~ 1e-22 -- exact to f32. Work drops 8x.

#define BETA 0.9f
#define THRESH 1.0f

constexpr int Bn = 16;
constexpr int Tn = 4096;
constexpr int Dn = 1024;
constexpr int En = 64;
constexpr int KTAIL = 512;                 // 0.9^512 ~ 4e-24: exact to f32
constexpr int ROWS = Bn * KTAIL;           // 8192 GEMM rows

// ---------------------------------------------------------------------------
// GEMM: P[dch][row][e] = sum_{d in chunk} seq[row][d] * W[e][d]
// 256 threads = 4 waves. lane = row within 64-row tile; wave owns 16 e-cols.
// W is read wave-uniformly -> scalar loads (s_load), so VALU is pure FMA.
// seq tile staged via float4 + XOR swizzle (conflict-free writes AND reads).
// ---------------------------------------------------------------------------
template <int DLEN>
__global__ __launch_bounds__(256, 2) void lif_gemm(const float* __restrict__ seq,
                                                   const float* __restrict__ W,
                                                   float* __restrict__ P) {
    constexpr int NDCH = Dn / DLEN;
    const int wg = blockIdx.x;
    const int rowblk = wg / NDCH;
    const int dch = wg % NDCH;
    const int t = threadIdx.x;
    const int lane = t & 63;
    const int wid = __builtin_amdgcn_readfirstlane(t >> 6);  // force SGPR
    const int e0 = wid * 16;

    const int row0 = rowblk * 64;          // global row base (all same batch b)
    const int b = row0 >> 9;               // KTAIL = 512
    const int k0 = row0 & (KTAIL - 1);
    const size_t seq_base = (size_t)(b * Tn + (Tn - KTAIL) + k0) * Dn;
    const float4* seq4 = reinterpret_cast<const float4*>(seq + seq_base);

    __shared__ float4 s_tile[64][32];      // 32 KB, [row][chunk^ (row&31)]

    float acc[16];
#pragma unroll
    for (int i = 0; i < 16; ++i) acc[i] = 0.f;

    for (int d0 = dch * DLEN; d0 < dch * DLEN + DLEN; d0 += 128) {
        __syncthreads();  // tile reuse guard
#pragma unroll
        for (int p = 0; p < 8; ++p) {
            int L = p * 256 + t;
            int r = L >> 5;
            int c4 = L & 31;
            s_tile[r][c4 ^ (r & 31)] = seq4[(size_t)r * (Dn / 4) + (d0 >> 2) + c4];
        }
        __syncthreads();

#pragma unroll 4
        for (int d4 = 0; d4 < 32; ++d4) {
            float4 sv = s_tile[lane][d4 ^ (lane & 31)];
            const int dbase = d0 + d4 * 4;
#pragma unroll
            for (int ee = 0; ee < 16; ++ee) {
                const float* wrow = W + (size_t)(e0 + ee) * Dn + dbase;  // uniform -> s_load
                acc[ee] = fmaf(sv.x, wrow[0], acc[ee]);
                acc[ee] = fmaf(sv.y, wrow[1], acc[ee]);
                acc[ee] = fmaf(sv.z, wrow[2], acc[ee]);
                acc[ee] = fmaf(sv.w, wrow[3], acc[ee]);
            }
        }
    }

    // write this d-chunk's partial I: P[dch][row0+lane][e0..e0+16)
    float* dst = P + ((size_t)dch * ROWS + row0 + lane) * En + e0;
    float4* dst4 = reinterpret_cast<float4*>(dst);
#pragma unroll
    for (int g = 0; g < 4; ++g)
        dst4[g] = make_float4(acc[4 * g], acc[4 * g + 1], acc[4 * g + 2], acc[4 * g + 3]);
}

// ---------------------------------------------------------------------------
// Scan + softmax: one block per batch, thread e runs the recurrence.
// ---------------------------------------------------------------------------
template <int NPART>
__global__ __launch_bounds__(64) void lif_scan(const float* __restrict__ P,
                                               const float* __restrict__ bias,
                                               float* __restrict__ out) {
    const int b = blockIdx.x;
    const int e = threadIdx.x;
    const float be = bias[e];
    const float* base = P + (size_t)(b * KTAIL) * En + e;

    float U = 0.f;  // truncated start: error <= |U_true| * 0.9^512 ~ 1e-22
#pragma unroll 4
    for (int k = 0; k < KTAIL; ++k) {
        float I = be;
#pragma unroll
        for (int p = 0; p < NPART; ++p)
            I += base[(size_t)p * ROWS * En + (size_t)k * En];
        U = fminf(fmaf(BETA, U, I), THRESH);
    }

    // softmax across the 64 lanes (e-dimension)
    float m = U;
#pragma unroll
    for (int mask = 32; mask; mask >>= 1)
        m = fmaxf(m, __shfl_xor(m, mask, 64));
    float ex = expf(U - m);
    float s = ex;
#pragma unroll
    for (int mask = 32; mask; mask >>= 1)
        s += __shfl_xor(s, mask, 64);
    out[b * En + e] = ex / s;
}

extern "C" void kernel_launch(void* const* d_in, const int* in_sizes, int n_in,
                              void* d_out, int out_size, void* d_ws, size_t ws_size,
                              hipStream_t stream) {
    const float* seq = (const float*)d_in[0];
    const float* W = (const float*)d_in[1];
    const float* bias = (const float*)d_in[2];
    float* out = (float*)d_out;
    float* P = (float*)d_ws;

    const size_t part_bytes = (size_t)ROWS * En * sizeof(float);  // 2 MB

    if (ws_size >= 4 * part_bytes) {
        lif_gemm<256><<<dim3((ROWS / 64) * 4), dim3(256), 0, stream>>>(seq, W, P);
        lif_scan<4><<<dim3(Bn), dim3(64), 0, stream>>>(P, bias, out);
    } else if (ws_size >= 2 * part_bytes) {
        lif_gemm<512><<<dim3((ROWS / 64) * 2), dim3(256), 0, stream>>>(seq, W, P);
        lif_scan<2><<<dim3(Bn), dim3(64), 0, stream>>>(P, bias, out);
    } else {
        lif_gemm<1024><<<dim3(ROWS / 64), dim3(256), 0, stream>>>(seq, W, P);
        lif_scan<1><<<dim3(Bn), dim3(64), 0, stream>>>(P, bias, out);
    }
}

// Round 2
// 40.439 us; speedup vs baseline: 2.8791x; 2.8791x over previous
//
#include <hip/hip_runtime.h>
#include <math.h>

// LIF router: I = seq @ W^T + b, then U_{t+1} = min(beta*U_t + I_t, 1), softmax(U_T).
//
// Exploit 1: min(.,1) is 1-Lipschitz, beta=0.9 -> timestep t influence <= 0.9^(T-1-t).
//   Last KTAIL=512 steps suffice (error ~1e-23). 8x work cut, exact to f32.
// Exploit 2: U -> min(a*U+b, c) is closed under composition & associative:
//   b' = a2*b1 + b2 ; c' = min(a2*c1 + b2, c2). So the scan parallelizes:
//   K2 computes 16-step chunk tuples with 32K threads, K3 folds 32 tuples/(b,e).
// Exploit 3 (vs round 1): W via LDS uniform-broadcast ds_read_b128, NOT s_load --
//   round 1 pushed 32 MB through the scalar pipe and stalled on lgkmcnt.

#define BETA 0.9f

constexpr int Bn = 16, Tn = 4096, Dn = 1024, En = 64;
constexpr int KTAIL = 512;
constexpr int ROWS = Bn * KTAIL;          // 8192 GEMM rows (row = b*512 + k_tail)
constexpr int RT = 128;                   // rows per GEMM tile
constexpr int NDCH = 8, DCH = 128;        // d chunks of 128
constexpr int CHK = 16;                   // scan chunk length
constexpr int NCHK = KTAIL / CHK;         // 32 chunks per batch
constexpr float A_CHK = 0.18530201888518416f;  // 0.9^16

// ---------------------------------------------------------------------------
// K1: P[dch][row][e] = sum_{d in chunk} seq[row][d] * W[e][d]
// 256 thr = 4 waves; lane = row (x2 row-groups), wave owns 16 e-columns.
// W[64][128] staged in LDS, read wave-uniform (broadcast, conflict-free).
// seq staged in 32-d stages with quad swizzle c^(r&7): per-lane b128 reads
// spread uniformly over 8 bank-quads = bandwidth floor, no hot bank.
// ---------------------------------------------------------------------------
__global__ __launch_bounds__(256, 2) void lif_gemm(const float4* __restrict__ seq4,
                                                   const float4* __restrict__ W4,
                                                   float* __restrict__ P) {
    const int rb = blockIdx.x >> 3;        // 64 row-blocks
    const int dch = blockIdx.x & 7;        // %8 round-robin == per-XCD W locality
    const int t = threadIdx.x;
    const int lane = t & 63;
    const int wid = __builtin_amdgcn_readfirstlane(t >> 6);
    const int e0 = wid * 16;

    const int row0 = rb * RT;              // 128 | 512 -> tile never crosses batch
    const int b = row0 >> 9;
    const int k0 = row0 & (KTAIL - 1);
    const float4* sq = seq4 + (size_t)(b * Tn + (Tn - KTAIL) + k0) * (Dn / 4)
                            + (size_t)dch * (DCH / 4);

    __shared__ float4 sW[64][32];          // [e][d-quad], 32 KB
    __shared__ float4 sS[RT][8];           // [row][quad ^ (row&7)], 16 KB

    // stage W chunk once (coalesced 256B per 16 threads)
#pragma unroll
    for (int i = 0; i < 8; ++i) {
        int L = i * 256 + t, e = L >> 5, q = L & 31;
        sW[e][q] = W4[(size_t)e * (Dn / 4) + dch * 32 + q];
    }

    float acc0[16], acc1[16];
#pragma unroll
    for (int i = 0; i < 16; ++i) { acc0[i] = 0.f; acc1[i] = 0.f; }

    for (int st = 0; st < 4; ++st) {       // 4 stages of 32 d
        __syncthreads();                   // also covers sW on st==0
#pragma unroll
        for (int i = 0; i < 4; ++i) {
            int L = i * 256 + t, r = L >> 3, c = L & 7;
            sS[r][c ^ (r & 7)] = sq[(size_t)r * (Dn / 4) + st * 8 + c];
        }
        __syncthreads();

#pragma unroll 2
        for (int d4 = 0; d4 < 8; ++d4) {
            const int sc = d4 ^ (lane & 7);        // (lane+64)&7 == lane&7
            const float4 s0 = sS[lane][sc];
            const float4 s1 = sS[lane + 64][sc];
#pragma unroll
            for (int ee = 0; ee < 16; ++ee) {
                const float4 w = sW[e0 + ee][st * 8 + d4];   // wave-uniform broadcast
                acc0[ee] = fmaf(s0.x, w.x, fmaf(s0.y, w.y,
                           fmaf(s0.z, w.z, fmaf(s0.w, w.w, acc0[ee]))));
                acc1[ee] = fmaf(s1.x, w.x, fmaf(s1.y, w.y,
                           fmaf(s1.z, w.z, fmaf(s1.w, w.w, acc1[ee]))));
            }
        }
    }

    // write this d-chunk's partial I
#pragma unroll
    for (int g = 0; g < 2; ++g) {
        const float* a = g ? acc1 : acc0;
        float4* dst = reinterpret_cast<float4*>(
            P + ((size_t)dch * ROWS + row0 + g * 64 + lane) * En + e0);
#pragma unroll
        for (int j = 0; j < 4; ++j)
            dst[j] = make_float4(a[4 * j], a[4 * j + 1], a[4 * j + 2], a[4 * j + 3]);
    }
}

// ---------------------------------------------------------------------------
// K2: per (b, 16-step chunk, e) compose the min-affine tuple (bb, cc).
// 128 blocks x 256 thr = 32K threads; loads coalesced 256B across e-lanes.
// ---------------------------------------------------------------------------
__global__ __launch_bounds__(256) void lif_compose(const float* __restrict__ P,
                                                   const float* __restrict__ bias,
                                                   float2* __restrict__ tup) {
    const int blk = blockIdx.x;            // 128
    const int b = blk >> 3, kb = blk & 7;
    const int t = threadIdx.x;
    const int e = t & 63, c = t >> 6;
    const int k0 = kb * 64 + c * CHK;
    const float be = bias[e];
    const float* base = P + (size_t)(b * KTAIL + k0) * En + e;

    float bb = 0.f, cc = 1e30f;            // identity: U -> min(U+0, inf)
#pragma unroll 4
    for (int j = 0; j < CHK; ++j) {
        float I = be;
#pragma unroll
        for (int p = 0; p < NDCH; ++p)
            I += base[(size_t)p * ROWS * En + (size_t)j * En];
        bb = fmaf(BETA, bb, I);                     // b <- beta*b + I
        cc = fminf(fmaf(BETA, cc, I), 1.0f);        // c <- min(beta*c + I, 1)
    }
    tup[(size_t)(b * NCHK + kb * 4 + c) * En + e] = make_float2(bb, cc);
}

// ---------------------------------------------------------------------------
// K3: fold 32 chunk tuples in k-order (a = beta^16 const), U = min(B,C), softmax.
// ---------------------------------------------------------------------------
__global__ __launch_bounds__(64) void lif_final(const float2* __restrict__ tup,
                                                float* __restrict__ out) {
    const int b = blockIdx.x;
    const int e = threadIdx.x;
    float B = 0.f, C = 1e30f;
#pragma unroll 8
    for (int ch = 0; ch < NCHK; ++ch) {
        const float2 g = tup[(size_t)(b * NCHK + ch) * En + e];
        B = fmaf(A_CHK, B, g.x);                    // B' = a*B + b_g
        C = fminf(fmaf(A_CHK, C, g.x), g.y);        // C' = min(a*C + b_g, c_g)
    }
    float U = fminf(B, C);

    float m = U;
#pragma unroll
    for (int mask = 32; mask; mask >>= 1)
        m = fmaxf(m, __shfl_xor(m, mask, 64));
    const float ex = expf(U - m);
    float s = ex;
#pragma unroll
    for (int mask = 32; mask; mask >>= 1)
        s += __shfl_xor(s, mask, 64);
    out[b * En + e] = ex / s;
}

extern "C" void kernel_launch(void* const* d_in, const int* in_sizes, int n_in,
                              void* d_out, int out_size, void* d_ws, size_t ws_size,
                              hipStream_t stream) {
    const float4* seq4 = (const float4*)d_in[0];
    const float4* W4 = (const float4*)d_in[1];
    const float* bias = (const float*)d_in[2];
    float* out = (float*)d_out;

    float* P = (float*)d_ws;                               // 8*8192*64*4 = 16 MB
    float2* tup = (float2*)((char*)d_ws + (size_t)NDCH * ROWS * En * sizeof(float));

    lif_gemm<<<dim3((ROWS / RT) * NDCH), dim3(256), 0, stream>>>(seq4, W4, P);
    lif_compose<<<dim3(Bn * 8), dim3(256), 0, stream>>>(P, bias, tup);
    lif_final<<<dim3(Bn), dim3(64), 0, stream>>>(tup, out);
}

// Round 3
// 25.281 us; speedup vs baseline: 4.6053x; 1.5996x over previous
//
#include <hip/hip_runtime.h>
#include <math.h>

// LIF router: I = seq @ W^T + b ; U <- min(beta*U + I_t, 1) over T ; softmax(U_T).
//
// Exploits:
//  1) min(.,1) is 1-Lipschitz, beta=0.9 -> only last KTAIL=256 steps matter
//     (error 0.9^256*|U| ~ 3e-11; threshold is 1.3e-3).
//  2) U -> min(a*U+b, c) is closed under composition (b'=a2*b1+b2,
//     c'=min(a2*c1+b2,c2)) -> scan parallelizes over 16-step chunks.
//  3) Split-bf16 MFMA: x = hi + lo (bf16 each); A*B ~ AhBh + AhBl + AlBh.
//     Per-product rel err ~2^-17 -> I err ~1e-5. Matrix cores do the operand
//     broadcast in HW (the f32-VALU version was LDS-pipe-bound on W broadcasts).
//  4) Full fusion: each wg owns one (batch, 16-step chunk), computes I over all
//     d in-LDS, composes the tuple locally. No 16 MB P round-trip, no K2.

typedef __attribute__((ext_vector_type(8))) short short8;
typedef __attribute__((ext_vector_type(4))) float f32x4;

#define BETA 0.9f
constexpr int Bn = 16, Tn = 4096, Dn = 1024, En = 64;
constexpr int KTAIL = 256, CHK = 16, NCHK = KTAIL / CHK;  // 16 chunks/batch
constexpr float A16 = 0.18530201888518416f;               // 0.9^16

__device__ __forceinline__ unsigned short f2bf(float x) {  // f32 -> bf16 RNE
    unsigned u = __float_as_uint(x);
    u += 0x7fffu + ((u >> 16) & 1u);
    return (unsigned short)(u >> 16);
}

// ---------------------------------------------------------------------------
// K0: convert W (f32 [E][D]) to bf16 hi/lo in B-fragment-linear layout:
//   idx = ((nt*32 + ks)*64 + lane)*8 + j   (ushort)
//   value = W[e = nt*16 + (lane&15)][d = ks*32 + (lane>>4)*8 + j]
// One u32 (2 bf16) per thread.
// ---------------------------------------------------------------------------
__global__ __launch_bounds__(256) void wprep(const float* __restrict__ W,
                                             unsigned int* __restrict__ Wh,
                                             unsigned int* __restrict__ Wl) {
    const int p = blockIdx.x * 256 + threadIdx.x;  // 0..32767
    const int j0 = (p & 3) * 2;
    const int l = (p >> 2) & 63;
    const int ks = (p >> 8) & 31;
    const int nt = p >> 13;
    const int e = nt * 16 + (l & 15);
    const int d = ks * 32 + (l >> 4) * 8 + j0;
    const float x0 = W[e * Dn + d], x1 = W[e * Dn + d + 1];
    const unsigned short h0 = f2bf(x0), h1 = f2bf(x1);
    const float r0 = x0 - __uint_as_float((unsigned)h0 << 16);
    const float r1 = x1 - __uint_as_float((unsigned)h1 << 16);
    Wh[p] = (unsigned)h0 | ((unsigned)h1 << 16);
    Wl[p] = (unsigned)f2bf(r0) | ((unsigned)f2bf(r1) << 16);
}

// ---------------------------------------------------------------------------
// K1: fused GEMM(16x64x1024, split-bf16 MFMA) + min-affine compose per chunk.
// Grid 256 = (b, chunk). 4 waves split K (wave w: d in [w*256, w*256+256)).
// A staged f32 in LDS (64 KB, row-XOR swizzle at 16B granularity), converted
// to hi/lo bf16 frags in-register. B frags straight from L2 (256 KB resident).
// ---------------------------------------------------------------------------
__global__ __launch_bounds__(256) void lif_main(const float4* __restrict__ seq4,
                                                const short8* __restrict__ BH,
                                                const short8* __restrict__ BL,
                                                const float* __restrict__ bias,
                                                float2* __restrict__ tup) {
    __shared__ float4 sA[4096];  // 16 rows x 1024 d f32 = 64 KB
    const int wg = blockIdx.x;
    const int b = wg >> 4, ch = wg & 15;
    const int t = threadIdx.x, lane = t & 63, wv = t >> 6;
    const int t0 = Tn - KTAIL + ch * CHK;
    const float4* tile = seq4 + (size_t)(b * Tn + t0) * (Dn / 4);

    // stage: global reads linear-coalesced; swizzle applied on the LDS write
    // (slot = row*256 + (c ^ (row&7)), 16B units) so frag reads are ~2-way.
#pragma unroll
    for (int i = 0; i < 16; ++i) {
        const int u = i * 256 + t, row = u >> 8, cp = u & 255;
        const float4 v = tile[u];
        sA[(row << 8) | (cp ^ (row & 7))] = v;
    }
    __syncthreads();

    f32x4 acc[4];
#pragma unroll
    for (int i = 0; i < 4; ++i) {
        acc[i][0] = 0.f; acc[i][1] = 0.f; acc[i][2] = 0.f; acc[i][3] = 0.f;
    }

    const int m = lane & 15, g = lane >> 4;  // A-frag: row=m, k=(g*8+j)
#pragma unroll
    for (int kk = 0; kk < 8; ++kk) {
        const int ks = wv * 8 + kk;          // K-step (K=32 each)
        const int c0 = ks * 8 + g * 2;       // 16B-chunk index of k-slice
        const float4 a0 = sA[(m << 8) | (c0 ^ (m & 7))];
        const float4 a1 = sA[(m << 8) | ((c0 + 1) ^ (m & 7))];
        short8 ah, al;
#define CVT(slot, val)                                                      \
        { const float xv = (val); const unsigned short h = f2bf(xv);        \
          ah[slot] = (short)h;                                              \
          al[slot] = (short)f2bf(xv - __uint_as_float((unsigned)h << 16)); }
        CVT(0, a0.x) CVT(1, a0.y) CVT(2, a0.z) CVT(3, a0.w)
        CVT(4, a1.x) CVT(5, a1.y) CVT(6, a1.z) CVT(7, a1.w)
#undef CVT
#pragma unroll
        for (int nt = 0; nt < 4; ++nt) {
            const int bi = (nt * 32 + ks) * 64 + lane;
            const short8 bh = BH[bi];
            const short8 bl = BL[bi];
            acc[nt] = __builtin_amdgcn_mfma_f32_16x16x32_bf16(ah, bh, acc[nt], 0, 0, 0);
            acc[nt] = __builtin_amdgcn_mfma_f32_16x16x32_bf16(al, bh, acc[nt], 0, 0, 0);
            acc[nt] = __builtin_amdgcn_mfma_f32_16x16x32_bf16(ah, bl, acc[nt], 0, 0, 0);
        }
    }
    __syncthreads();  // all frag reads done -> safe to alias sA

    // C-frag (m89-verified): lane holds D[r=(lane>>4)*4+q][e16=lane&15]
    float* sC = (float*)sA;  // [wave][16 r][64 e] partials, 16 KB
#pragma unroll
    for (int nt = 0; nt < 4; ++nt)
#pragma unroll
        for (int q = 0; q < 4; ++q)
            sC[(wv * 16 + g * 4 + q) * 64 + nt * 16 + m] = acc[nt][q];
    __syncthreads();

    if (t < 64) {  // lane = e: reduce 4 K-partials + bias, compose 16 steps
        const float be = bias[t];
        float bb = 0.f, cc = 1e30f;  // identity: U -> min(U + 0, inf)
#pragma unroll
        for (int r = 0; r < CHK; ++r) {
            const float I = sC[(0 * 16 + r) * 64 + t] + sC[(1 * 16 + r) * 64 + t] +
                            sC[(2 * 16 + r) * 64 + t] + sC[(3 * 16 + r) * 64 + t] + be;
            bb = fmaf(BETA, bb, I);
            cc = fminf(fmaf(BETA, cc, I), 1.0f);
        }
        tup[(b * NCHK + ch) * En + t] = make_float2(bb, cc);
    }
}

// ---------------------------------------------------------------------------
// K2: fold 16 chunk tuples in k-order (a = 0.9^16), U = min(B,C), softmax.
// ---------------------------------------------------------------------------
__global__ __launch_bounds__(64) void lif_final(const float2* __restrict__ tup,
                                                float* __restrict__ out) {
    const int b = blockIdx.x;
    const int e = threadIdx.x;
    float Bv = 0.f, Cv = 1e30f;
#pragma unroll
    for (int c = 0; c < NCHK; ++c) {
        const float2 gg = tup[(b * NCHK + c) * En + e];
        Bv = fmaf(A16, Bv, gg.x);
        Cv = fminf(fmaf(A16, Cv, gg.x), gg.y);
    }
    const float U = fminf(Bv, Cv);

    float mx = U;
#pragma unroll
    for (int mask = 32; mask; mask >>= 1)
        mx = fmaxf(mx, __shfl_xor(mx, mask, 64));
    const float ex = expf(U - mx);
    float s = ex;
#pragma unroll
    for (int mask = 32; mask; mask >>= 1)
        s += __shfl_xor(s, mask, 64);
    out[b * En + e] = ex / s;
}

extern "C" void kernel_launch(void* const* d_in, const int* in_sizes, int n_in,
                              void* d_out, int out_size, void* d_ws, size_t ws_size,
                              hipStream_t stream) {
    const float4* seq4 = (const float4*)d_in[0];
    const float* W = (const float*)d_in[1];
    const float* bias = (const float*)d_in[2];
    float* out = (float*)d_out;

    unsigned int* Wh = (unsigned int*)d_ws;                        // 128 KB
    unsigned int* Wl = (unsigned int*)((char*)d_ws + 131072);      // 128 KB
    float2* tup = (float2*)((char*)d_ws + 262144);                 // 128 KB

    wprep<<<dim3(128), dim3(256), 0, stream>>>(W, Wh, Wl);
    lif_main<<<dim3(Bn * NCHK), dim3(256), 0, stream>>>(
        seq4, (const short8*)Wh, (const short8*)Wl, bias, tup);
    lif_final<<<dim3(Bn), dim3(64), 0, stream>>>(tup, out);
}

// Round 4
// 16.726 us; speedup vs baseline: 6.9607x; 1.5115x over previous
//
#include <hip/hip_runtime.h>
#include <math.h>

// LIF router: I = seq @ W^T + b ; U <- min(beta*U + I_t, 1) over T ; softmax(U_T).
//
// Exploits:
//  1) min(.,1) is 1-Lipschitz, beta=0.9 -> only last KTAIL=256 steps matter
//     (error 0.9^256*|U| ~ 3e-11; threshold 1.3e-3).
//  2) U -> min(a*U+b, c) closed under composition -> scan parallelizes over
//     16-step chunks; tiny final kernel folds 16 tuples per (b,e).
//  3) Split-bf16 MFMA: x = hi+lo, A*B ~ AhBh + AlBh + AhBl (err ~1e-5).
//  4) Round-4 fusion: W f32 -> split-bf16 fragment conversion happens INSIDE
//     the main kernel, per wave, from L2 (256 KB W is L2-resident per XCD).
//     Removes the wprep dispatch + its graph gap + 768 KB of HBM round-trip;
//     convert VALU (~1 us/wave) hides under the 2.7 us seq-staging stream.

typedef __attribute__((ext_vector_type(8))) short short8;
typedef __attribute__((ext_vector_type(4))) float f32x4;

#define BETA 0.9f
constexpr int Bn = 16, Tn = 4096, Dn = 1024, En = 64;
constexpr int KTAIL = 256, CHK = 16, NCHK = KTAIL / CHK;  // 16 chunks/batch
constexpr float A16 = 0.18530201888518416f;               // 0.9^16

__device__ __forceinline__ unsigned short f2bf(float x) {  // f32 -> bf16 RNE
    unsigned u = __float_as_uint(x);
    u += 0x7fffu + ((u >> 16) & 1u);
    return (unsigned short)(u >> 16);
}

// ---------------------------------------------------------------------------
// K1: fused { seq-tile stage -> W gather+convert -> split-bf16 MFMA GEMM
//             -> 8-way K reduce -> 16-step min-affine compose }.
// Grid 256 = (b, chunk); 512 thr = 8 waves, wave wv owns K-range
// [wv*128, wv*128+128) (ks = wv*4+kk, K=32 per MFMA step).
// ---------------------------------------------------------------------------
__global__ __launch_bounds__(512, 2) void lif_fused(const float4* __restrict__ seq4,
                                                    const float* __restrict__ W,
                                                    const float* __restrict__ bias,
                                                    float2* __restrict__ tup) {
    __shared__ float4 sA[4096];  // 16 rows x 1024 d f32 = 64 KB
    const int bid = blockIdx.x;
    const int b = bid >> 4, ch = bid & 15;
    const int t = threadIdx.x, lane = t & 63;
    const int wv = __builtin_amdgcn_readfirstlane(t >> 6);
    const int t0 = Tn - KTAIL + ch * CHK;
    const float4* tile = seq4 + (size_t)(b * Tn + t0) * (Dn / 4);

    // stage: global reads linear-coalesced (1 KB/wave/iter); swizzle on the
    // LDS write (slot = row*256 + (c ^ (row&7)), 16B units) -> frag reads
    // spread uniformly over bank-quads (verified round 3).
#pragma unroll
    for (int i = 0; i < 8; ++i) {
        const int u = i * 512 + t, row = u >> 8, cp = u & 255;
        const float4 v = tile[u];
        sA[(row << 8) | (cp ^ (row & 7))] = v;
    }
    __syncthreads();

    f32x4 acc[4];
#pragma unroll
    for (int i = 0; i < 4; ++i) {
        acc[i][0] = 0.f; acc[i][1] = 0.f; acc[i][2] = 0.f; acc[i][3] = 0.f;
    }

    const int m = lane & 15, g = lane >> 4;

#define CVT(dh, dl, slot, val)                                              \
    { const float xv = (val); const unsigned short h = f2bf(xv);            \
      dh[slot] = (short)h;                                                  \
      dl[slot] = (short)f2bf(xv - __uint_as_float((unsigned)h << 16)); }

#pragma unroll
    for (int kk = 0; kk < 4; ++kk) {
        const int ks = wv * 4 + kk;          // K-step (K=32 each)
        // A-frag from LDS: row=m, k=g*8+j  -> f32 idx ks*32+g*8+j
        const int c0 = ks * 8 + g * 2;
        const float4 a0 = sA[(m << 8) | (c0 ^ (m & 7))];
        const float4 a1 = sA[(m << 8) | ((c0 + 1) ^ (m & 7))];
        short8 ah, al;
        CVT(ah, al, 0, a0.x) CVT(ah, al, 1, a0.y) CVT(ah, al, 2, a0.z) CVT(ah, al, 3, a0.w)
        CVT(ah, al, 4, a1.x) CVT(ah, al, 5, a1.y) CVT(ah, al, 6, a1.z) CVT(ah, al, 7, a1.w)

#pragma unroll
        for (int nt = 0; nt < 4; ++nt) {
            // B-frag straight from L2: e = nt*16+m, d = ks*32+g*8+j
            // (layout bit-exact-verified by round 3's wprep path)
            const float* wp = W + (size_t)(nt * 16 + m) * Dn + ks * 32 + g * 8;
            const float4 w0 = *(const float4*)wp;
            const float4 w1 = *(const float4*)(wp + 4);
            short8 bh, bl;
            CVT(bh, bl, 0, w0.x) CVT(bh, bl, 1, w0.y) CVT(bh, bl, 2, w0.z) CVT(bh, bl, 3, w0.w)
            CVT(bh, bl, 4, w1.x) CVT(bh, bl, 5, w1.y) CVT(bh, bl, 6, w1.z) CVT(bh, bl, 7, w1.w)
            acc[nt] = __builtin_amdgcn_mfma_f32_16x16x32_bf16(ah, bh, acc[nt], 0, 0, 0);
            acc[nt] = __builtin_amdgcn_mfma_f32_16x16x32_bf16(al, bh, acc[nt], 0, 0, 0);
            acc[nt] = __builtin_amdgcn_mfma_f32_16x16x32_bf16(ah, bl, acc[nt], 0, 0, 0);
        }
    }
#undef CVT
    __syncthreads();  // all sA frag reads done -> safe to alias

    // C-frag (m89-verified): lane holds D[r=g*4+q][e16=m]
    float* sC = (float*)sA;  // [wave][16 r][64 e], 32 KB
#pragma unroll
    for (int nt = 0; nt < 4; ++nt)
#pragma unroll
        for (int q = 0; q < 4; ++q)
            sC[(wv * 16 + g * 4 + q) * 64 + nt * 16 + m] = acc[nt][q];
    __syncthreads();

    // 8-way K-partial reduce + bias: 1024 (r,e) cells over 512 threads
    float* sI = (float*)sA + 8192;  // byte 32768, [16 r][64 e] = 4 KB
#pragma unroll
    for (int h = 0; h < 2; ++h) {
        const int idx = h * 512 + t, r = idx >> 6, e = idx & 63;
        float s = bias[e];
#pragma unroll
        for (int w = 0; w < 8; ++w) s += sC[(w * 16 + r) * 64 + e];
        sI[r * 64 + e] = s;
    }
    __syncthreads();

    if (t < 64) {  // lane = e: compose the 16-step min-affine tuple
        float bb = 0.f, cc = 1e30f;  // identity: U -> min(U + 0, inf)
#pragma unroll
        for (int r = 0; r < CHK; ++r) {
            const float I = sI[r * 64 + t];
            bb = fmaf(BETA, bb, I);
            cc = fminf(fmaf(BETA, cc, I), 1.0f);
        }
        tup[(b * NCHK + ch) * En + t] = make_float2(bb, cc);
    }
}

// ---------------------------------------------------------------------------
// K2: fold 16 chunk tuples in k-order (a = 0.9^16), U = min(B,C), softmax.
// ---------------------------------------------------------------------------
__global__ __launch_bounds__(64) void lif_final(const float2* __restrict__ tup,
                                                float* __restrict__ out) {
    const int b = blockIdx.x;
    const int e = threadIdx.x;
    float Bv = 0.f, Cv = 1e30f;
#pragma unroll
    for (int c = 0; c < NCHK; ++c) {
        const float2 gg = tup[(b * NCHK + c) * En + e];
        Bv = fmaf(A16, Bv, gg.x);
        Cv = fminf(fmaf(A16, Cv, gg.x), gg.y);
    }
    const float U = fminf(Bv, Cv);

    float mx = U;
#pragma unroll
    for (int mask = 32; mask; mask >>= 1)
        mx = fmaxf(mx, __shfl_xor(mx, mask, 64));
    const float ex = expf(U - mx);
    float s = ex;
#pragma unroll
    for (int mask = 32; mask; mask >>= 1)
        s += __shfl_xor(s, mask, 64);
    out[b * En + e] = ex / s;
}

extern "C" void kernel_launch(void* const* d_in, const int* in_sizes, int n_in,
                              void* d_out, int out_size, void* d_ws, size_t ws_size,
                              hipStream_t stream) {
    const float4* seq4 = (const float4*)d_in[0];
    const float* W = (const float*)d_in[1];
    const float* bias = (const float*)d_in[2];
    float* out = (float*)d_out;
    float2* tup = (float2*)d_ws;  // 16*16*64*8 = 128 KB

    lif_fused<<<dim3(Bn * NCHK), dim3(512), 0, stream>>>(seq4, W, bias, tup);
    lif_final<<<dim3(Bn), dim3(64), 0, stream>>>(tup, out);
}